// Round 5
// baseline (238.472 us; speedup 1.0000x reference)
//
#include <hip/hip_runtime.h>
#include <stdint.h>

typedef unsigned short u16;
typedef unsigned int   u32;
typedef __bf16 bf16;
typedef bf16  bf16x2 __attribute__((ext_vector_type(2)));
typedef bf16  bf16x8 __attribute__((ext_vector_type(8)));
typedef float f32x4  __attribute__((ext_vector_type(4)));

#define AS1 __attribute__((address_space(1)))
#define AS3 __attribute__((address_space(3)))

// ---------- helpers ----------

// pack two floats to bf16x2 (RNE) -> u32; compiler emits v_cvt_pk_bf16_f32
__device__ __forceinline__ u32 pk2(float lo, float hi) {
  bf16x2 t;
  t[0] = (bf16)lo;
  t[1] = (bf16)hi;
  return __builtin_bit_cast(u32, t);
}

__device__ __forceinline__ u16 b1(float f) {
  bf16 t = (bf16)f;
  return __builtin_bit_cast(u16, t);
}

__device__ __forceinline__ void gload_lds16(const void* src, void* dst) {
  // 16B per lane, HW dest = wave-uniform base + lane*16
  __builtin_amdgcn_global_load_lds((const AS1 void*)src, (AS3 void*)dst, 16, 0, 0);
}

// linear fragment read from a [rows][128B] LDS tile
__device__ __forceinline__ bf16x8 fragL(const char* lds, int row, int kbyte) {
  return *(const bf16x8*)(lds + row * 128 + kbyte);
}

// ---------- fp32 -> bf16 conversion (weights only) ----------

__global__ __launch_bounds__(256) void cvt_w(
    const float* wq, const float* wk, const float* wv, const float* wo,
    u16* wqb, u16* wkb, u16* wvb, u16* wob)
{
  const float* src; u16* dst;
  switch (blockIdx.y) {
    case 0: src = wq; dst = wqb; break;
    case 1: src = wk; dst = wkb; break;
    case 2: src = wv; dst = wvb; break;
    default: src = wo; dst = wob; break;
  }
  const int n4 = 262144;
  int stride = gridDim.x * blockDim.x;
  for (int i = blockIdx.x * blockDim.x + threadIdx.x; i < n4; i += stride) {
    float4 f = ((const float4*)src)[i];
    uint2 o;
    o.x = pk2(f.x, f.y);
    o.y = pk2(f.z, f.w);
    ((uint2*)dst)[i] = o;
  }
}

// ---------- GEMM staging ----------

// bf16 source -> linear LDS [128][64] via global_load_lds (m97-exact)
__device__ __forceinline__ void stageL(const u16* gtile, char* lds, int tid)
{
  int w = tid >> 6, lane = tid & 63;
  int rr = lane >> 3;               // row within 8-row chunk
  int cb = (lane & 7) << 4;         // byte col within 128B row
  #pragma unroll
  for (int i = 0; i < 4; ++i) {
    int c = i * 4 + w;              // chunk 0..15, 1KB each (8 rows)
    gload_lds16((const char*)(gtile + (c * 8 + rr) * 1024) + cb, lds + c * 1024);
  }
}

// fp32 source -> cvt -> linear LDS [128][64] bf16 (reg-staged, fuses cvt_all)
__device__ __forceinline__ void stageA_f32(const float* gA, char* lds, int tid)
{
  int r0 = tid >> 3;                // 0..31
  int c8 = (tid & 7) << 3;          // 0..56 step 8 (fp32 elems)
  #pragma unroll
  for (int i = 0; i < 4; ++i) {
    int r = i * 32 + r0;
    const float* p = gA + r * 1024 + c8;
    float4 f0 = *(const float4*)p;
    float4 f1 = *(const float4*)(p + 4);
    uint4 o;
    o.x = pk2(f0.x, f0.y);
    o.y = pk2(f0.z, f0.w);
    o.z = pk2(f1.x, f1.y);
    o.w = pk2(f1.z, f1.w);
    *(uint4*)(lds + r * 128 + (c8 << 1)) = o;
  }
}

// one K-tile of MFMAs on staged As/Bs
__device__ __forceinline__ void mfma_tile(const char* As, const char* Bs,
                                          f32x4 acc[4][4], int lane,
                                          int wr, int wc)
{
  #pragma unroll
  for (int ks = 0; ks < 2; ++ks) {
    int kb = ks * 64 + ((lane >> 4) << 4);
    bf16x8 af[4], bfr[4];
    #pragma unroll
    for (int m = 0; m < 4; ++m) af[m]  = fragL(As, wr * 64 + m * 16 + (lane & 15), kb);
    #pragma unroll
    for (int n = 0; n < 4; ++n) bfr[n] = fragL(Bs, wc * 64 + n * 16 + (lane & 15), kb);
    #pragma unroll
    for (int m = 0; m < 4; ++m)
      #pragma unroll
      for (int n = 0; n < 4; ++n)
        acc[m][n] = __builtin_amdgcn_mfma_f32_16x16x32_bf16(af[m], bfr[n], acc[m][n], 0, 0, 0);
  }
}

// ---------- QKV projection (z=0:Q, 1:K, 2:V), A read fp32 + fused cvt ------
// Q,K out: [B,H,T,D]  V out: [B,H,D,T] (transposed for attention PV)

__global__ __launch_bounds__(256, 2) void proj_gemm(
    const float* qf, const float* kf, const float* vf,
    const u16* wqb, const u16* wkb, const u16* wvb,
    const float* bq, const float* bk, const float* bv,
    u16* qh, u16* kh, u16* vt)
{
  __shared__ alignas(16) char As[16384];
  __shared__ alignas(16) char Bs[16384];
  int tid = threadIdx.x;
  int bi = blockIdx.x & 31, bj = blockIdx.x >> 5;
  int z = blockIdx.z;
  const float* A = (z == 0) ? qf : (z == 1) ? kf : vf;
  const u16* W = (z == 0) ? wqb : (z == 1) ? wkb : wvb;
  const float* bias = (z == 0) ? bq : (z == 1) ? bk : bv;
  u16* dst = (z == 0) ? qh : (z == 1) ? kh : vt;

  int lane = tid & 63;
  int wr = (tid >> 7) & 1, wc = (tid >> 6) & 1;
  f32x4 acc[4][4] = {};
  for (int kt = 0; kt < 16; ++kt) {
    stageA_f32(A + bi * 131072 + kt * 64, As, tid);
    stageL(W + bj * 131072 + kt * 64, Bs, tid);
    __syncthreads();
    mfma_tile(As, Bs, acc, lane, wr, wc);
    __syncthreads();
  }

  int rbase = bi * 128 + wr * 64 + ((lane >> 4) << 2);
  int cbase = bj * 128 + wc * 64;
  #pragma unroll
  for (int n = 0; n < 4; ++n) {
    int col = cbase + n * 16 + (lane & 15);
    float bsv = bias[col];
    int h = col >> 6, d = col & 63;
    #pragma unroll
    for (int m = 0; m < 4; ++m) {
      #pragma unroll
      for (int r = 0; r < 4; ++r) {
        int R = rbase + m * 16 + r;
        int b = R >> 10, t = R & 1023;
        u16 val = b1(acc[m][n][r] + bsv);
        if (z < 2) dst[(((b * 16 + h) * 1024 + t) << 6) + d] = val;
        else       dst[(((b * 16 + h) * 64 + d) << 10) + t] = val;
      }
    }
  }
}

// ---------- output projection: attn[4096x1024] @ Wo^T + bo -> FP32 d_out ----

__global__ __launch_bounds__(256, 2) void out_gemm(
    const u16* attn, const u16* wob, const float* bo, float* out)
{
  __shared__ alignas(16) char As[16384];
  __shared__ alignas(16) char Bs[16384];
  int tid = threadIdx.x;
  int bi = blockIdx.x & 31, bj = blockIdx.x >> 5;

  int lane = tid & 63;
  int wr = (tid >> 7) & 1, wc = (tid >> 6) & 1;
  f32x4 acc[4][4] = {};
  for (int kt = 0; kt < 16; ++kt) {
    stageL(attn + bi * 131072 + kt * 64, As, tid);
    stageL(wob  + bj * 131072 + kt * 64, Bs, tid);
    __syncthreads();
    mfma_tile(As, Bs, acc, lane, wr, wc);
    __syncthreads();
  }

  int rbase = bi * 128 + wr * 64 + ((lane >> 4) << 2);
  int cbase = bj * 128 + wc * 64;
  #pragma unroll
  for (int n = 0; n < 4; ++n) {
    int col = cbase + n * 16 + (lane & 15);
    float bsv = bo[col];
    #pragma unroll
    for (int m = 0; m < 4; ++m) {
      #pragma unroll
      for (int r = 0; r < 4; ++r) {
        int R = rbase + m * 16 + r;
        out[R * 1024 + col] = acc[m][n][r] + bsv;   // fp32 output
      }
    }
  }
}

// ---------- flash attention ----------
// grid (16, 64): x = q-tile (64 rows), y = b*16+h. 4 waves x 16 q-rows.
// Swapped QK^T: S^T = mfma(K, Q). PV: O^T = mfma(V^T, P^T).
// Softmax: raw-score online max (scale folded into exp via fma),
// T13 defer-max (THR = 8 nats -> 64 raw), native cvt_pk bf16 packing.

__global__ __launch_bounds__(256, 2) void attn_fwd(
    const u16* qh, const u16* kh, const u16* vt, u16* attnb)
{
  __shared__ alignas(16) u16 Ks[64 * 72];
  __shared__ alignas(16) u16 Vs[64 * 72];
  __shared__ alignas(16) u16 Pl[4][16 * 72];

  const float SC = 0.125f;           // 1/sqrt(64)
  const float RTHR = 64.0f;          // 8 nats / SC

  int tid = threadIdx.x, lane = tid & 63, w = tid >> 6;
  int g = lane >> 4;
  int q0 = blockIdx.x << 6;
  int bh = blockIdx.y;
  const u16* qbase = qh + bh * 65536;   // [t][d]
  const u16* kbase = kh + bh * 65536;   // [t][d]
  const u16* vbase = vt + bh * 65536;   // [d][t]

  // Q fragment (B-operand)
  bf16x8 qf[2];
  {
    int qrow = q0 + w * 16 + (lane & 15);
    const u16* p = qbase + qrow * 64 + (g << 3);
    qf[0] = *(const bf16x8*)p;
    qf[1] = *(const bf16x8*)(p + 32);
  }

  f32x4 ot[4] = {};
  float m_r = -3.0e38f, l_r = 0.f;   // m_r in RAW score units

  int sr = tid >> 2;                 // staging row 0..63
  int sj = (tid & 3) << 4;           // staging col {0,16,32,48}
  u16* pw = Pl[w];
  int prow = (lane & 15) * 72;

  for (int kv0 = 0; kv0 < 1024; kv0 += 64) {
    // stage K[kv][d] and V^T[d][kv] tiles
    {
      const u16* ksrc = kbase + (kv0 + sr) * 64 + sj;
      const u16* vsrc = vbase + sr * 1024 + kv0 + sj;
      *(bf16x8*)(Ks + sr * 72 + sj)     = *(const bf16x8*)ksrc;
      *(bf16x8*)(Ks + sr * 72 + sj + 8) = *(const bf16x8*)(ksrc + 8);
      *(bf16x8*)(Vs + sr * 72 + sj)     = *(const bf16x8*)vsrc;
      *(bf16x8*)(Vs + sr * 72 + sj + 8) = *(const bf16x8*)(vsrc + 8);
    }
    __syncthreads();

    // S^T = K * Q^T (raw scores)
    f32x4 sc[4] = {};
    #pragma unroll
    for (int ks = 0; ks < 2; ++ks) {
      #pragma unroll
      for (int m = 0; m < 4; ++m) {
        bf16x8 kf = *(const bf16x8*)(Ks + (m * 16 + (lane & 15)) * 72 + ks * 32 + g * 8);
        sc[m] = __builtin_amdgcn_mfma_f32_16x16x32_bf16(kf, qf[ks], sc[m], 0, 0, 0);
      }
    }

    // online softmax on raw scores (row q = lane&15; 4 lane-groups/row)
    float vmax = -3.0e38f;
    #pragma unroll
    for (int m = 0; m < 4; ++m)
      #pragma unroll
      for (int r = 0; r < 4; ++r)
        vmax = fmaxf(vmax, sc[m][r]);
    vmax = fmaxf(vmax, __shfl_xor(vmax, 16, 64));
    vmax = fmaxf(vmax, __shfl_xor(vmax, 32, 64));

    if (!__all(vmax - m_r <= RTHR)) {    // T13 defer-max
      float mnew = fmaxf(m_r, vmax);
      float fac = __expf((m_r - mnew) * SC);
      l_r *= fac;
      #pragma unroll
      for (int dm = 0; dm < 4; ++dm) ot[dm] *= fac;
      m_r = mnew;
    }
    float nm = -m_r * SC;

    float psum = 0.f;
    u32 pp[4][2];
    #pragma unroll
    for (int m = 0; m < 4; ++m) {
      float p0 = __expf(fmaf(sc[m][0], SC, nm));
      float p1 = __expf(fmaf(sc[m][1], SC, nm));
      float p2 = __expf(fmaf(sc[m][2], SC, nm));
      float p3 = __expf(fmaf(sc[m][3], SC, nm));
      psum += (p0 + p1) + (p2 + p3);
      pp[m][0] = pk2(p0, p1);
      pp[m][1] = pk2(p2, p3);
    }
    psum += __shfl_xor(psum, 16, 64);
    psum += __shfl_xor(psum, 32, 64);
    l_r += psum;

    // P -> per-wave LDS [16 q][72 kv] (bf16); lane writes kv = m*16+g*4..+3
    #pragma unroll
    for (int m = 0; m < 4; ++m) {
      u32* d = (u32*)(pw + prow + m * 16 + (g << 2));
      d[0] = pp[m][0];
      d[1] = pp[m][1];
    }

    // O^T += V^T * P^T
    #pragma unroll
    for (int ks = 0; ks < 2; ++ks) {
      bf16x8 pf = *(const bf16x8*)(pw + prow + ks * 32 + g * 8);
      #pragma unroll
      for (int dm = 0; dm < 4; ++dm) {
        bf16x8 vf = *(const bf16x8*)(Vs + (dm * 16 + (lane & 15)) * 72 + ks * 32 + g * 8);
        ot[dm] = __builtin_amdgcn_mfma_f32_16x16x32_bf16(vf, pf, ot[dm], 0, 0, 0);
      }
    }
    __syncthreads();
  }

  // normalize + write merged-head attn [4096][1024] bf16
  float inv = 1.0f / l_r;
  int b = bh >> 4, h = bh & 15;
  int tok = (b << 10) + q0 + w * 16 + (lane & 15);
  u16* obase = attnb + tok * 1024 + h * 64;
  #pragma unroll
  for (int dm = 0; dm < 4; ++dm) {
    int d0 = dm * 16 + (g << 2);
    u32* d = (u32*)(obase + d0);
    d[0] = pk2(ot[dm][0] * inv, ot[dm][1] * inv);
    d[1] = pk2(ot[dm][2] * inv, ot[dm][3] * inv);
  }
}

// ---------- launch ----------

extern "C" void kernel_launch(void* const* d_in, const int* in_sizes, int n_in,
                              void* d_out, int out_size, void* d_ws, size_t ws_size,
                              hipStream_t stream)
{
  const float* q  = (const float*)d_in[0];
  const float* k  = (const float*)d_in[1];
  const float* v  = (const float*)d_in[2];
  const float* Wq = (const float*)d_in[3];
  const float* bq = (const float*)d_in[4];
  const float* Wk = (const float*)d_in[5];
  const float* bk = (const float*)d_in[6];
  const float* Wv = (const float*)d_in[7];
  const float* bv = (const float*)d_in[8];
  const float* Wo = (const float*)d_in[9];
  const float* bo = (const float*)d_in[10];
  float* out = (float*)d_out;          // reference output dtype = float32

  u16* ws  = (u16*)d_ws;
  u16* wqb = ws;                    // 1M elems each (bf16)
  u16* wkb = wqb + (1u << 20);
  u16* wvb = wkb + (1u << 20);
  u16* wob = wvb + (1u << 20);
  u16* qhb = wob + (1u << 20);      // 4M each
  u16* khb = qhb + (4u << 20);
  u16* vtb = khb + (4u << 20);
  u16* atb = vtb + (4u << 20);      // total 40 MiB

  cvt_w<<<dim3(256, 4, 1), 256, 0, stream>>>(Wq, Wk, Wv, Wo, wqb, wkb, wvb, wob);
  proj_gemm<<<dim3(256, 1, 3), 256, 0, stream>>>(q, k, v, wqb, wkb, wvb,
                                                 bq, bk, bv, qhb, khb, vtb);
  attn_fwd<<<dim3(16, 64, 1), 256, 0, stream>>>(qhb, khb, vtb, atb);
  out_gemm<<<dim3(256, 1, 1), 256, 0, stream>>>(atb, wob, bo, out);
}

// Round 7
// 223.533 us; speedup vs baseline: 1.0668x; 1.0668x over previous
//
#include <hip/hip_runtime.h>
#include <stdint.h>

typedef unsigned short u16;
typedef unsigned int   u32;
typedef __bf16 bf16;
typedef bf16  bf16x2 __attribute__((ext_vector_type(2)));
typedef bf16  bf16x8 __attribute__((ext_vector_type(8)));
typedef float f32x4  __attribute__((ext_vector_type(4)));

#define AS1 __attribute__((address_space(1)))
#define AS3 __attribute__((address_space(3)))

// ---------- helpers ----------

// pack two floats to bf16x2 (RNE) -> u32 (v_cvt_pk_bf16_f32)
__device__ __forceinline__ u32 pk2(float lo, float hi) {
  bf16x2 t;
  t[0] = (bf16)lo;
  t[1] = (bf16)hi;
  return __builtin_bit_cast(u32, t);
}

__device__ __forceinline__ u16 b1(float f) {
  bf16 t = (bf16)f;
  return __builtin_bit_cast(u16, t);
}

__device__ __forceinline__ void gload_lds16(const void* src, void* dst) {
  // 16B per lane, HW dest = wave-uniform base + lane*16
  __builtin_amdgcn_global_load_lds((const AS1 void*)src, (AS3 void*)dst, 16, 0, 0);
}

// swizzled fragment read from a [rows][128B] LDS tile: byte ^= (row&7)<<4
__device__ __forceinline__ bf16x8 fragS(const char* lds, int row, int kbyte) {
  return *(const bf16x8*)(lds + row * 128 + (kbyte ^ ((row & 7) << 4)));
}

// ---------- fp32 -> bf16 conversion (weights only) ----------

__global__ __launch_bounds__(256) void cvt_w(
    const float* wq, const float* wk, const float* wv, const float* wo,
    u16* wqb, u16* wkb, u16* wvb, u16* wob)
{
  const float* src; u16* dst;
  switch (blockIdx.y) {
    case 0: src = wq; dst = wqb; break;
    case 1: src = wk; dst = wkb; break;
    case 2: src = wv; dst = wvb; break;
    default: src = wo; dst = wob; break;
  }
  const int n4 = 262144;
  int stride = gridDim.x * blockDim.x;
  for (int i = blockIdx.x * blockDim.x + threadIdx.x; i < n4; i += stride) {
    float4 f = ((const float4*)src)[i];
    uint2 o;
    o.x = pk2(f.x, f.y);
    o.y = pk2(f.z, f.w);
    ((uint2*)dst)[i] = o;
  }
}

// ---------- GEMM staging ----------

// bf16 source -> LDS [8*NC*4 rows][64k] via global_load_lds, PRE-SWIZZLED
// source (linear LDS dest; content ends up swizzled; read with fragS).
template<int NC>
__device__ __forceinline__ void stageSw(const u16* gtile, char* lds, int tid)
{
  int w = tid >> 6, lane = tid & 63;
  int rr = lane >> 3;                       // row within 8-row chunk == row&7
  int cb = (lane & 7) << 4;                 // byte col within 128B row
  #pragma unroll
  for (int i = 0; i < NC; ++i) {
    int c = i * 4 + w;                      // 1KB chunk index
    int r = c * 8 + rr;
    gload_lds16((const char*)(gtile + r * 1024) + (cb ^ (rr << 4)), lds + c * 1024);
  }
}

// fp32 A prefetch (T14 issue-early): 64 rows, per-thread 2x32B
__device__ __forceinline__ void loadA64(const float* gA, int tid,
                                        float4* pa, float4* pb)
{
  int r0 = tid >> 3, c8 = (tid & 7) << 3;
  #pragma unroll
  for (int i = 0; i < 2; ++i) {
    const float* p = gA + (i * 32 + r0) * 1024 + c8;
    pa[i] = *(const float4*)p;
    pb[i] = *(const float4*)(p + 4);
  }
}

// cvt + swizzled ds_write into [64][64] bf16 LDS
__device__ __forceinline__ void writeA64(char* lds, int tid,
                                         const float4* pa, const float4* pb)
{
  int r0 = tid >> 3, cb = (tid & 7) << 4;
  #pragma unroll
  for (int i = 0; i < 2; ++i) {
    int r = i * 32 + r0;
    uint4 o;
    o.x = pk2(pa[i].x, pa[i].y);
    o.y = pk2(pa[i].z, pa[i].w);
    o.z = pk2(pb[i].x, pb[i].y);
    o.w = pk2(pb[i].z, pb[i].w);
    *(uint4*)(lds + r * 128 + (cb ^ ((r & 7) << 4))) = o;
  }
}

// one K-tile of MFMAs: BM=64 (2 m-frags) x BN=128 (4 n-frags), waves 2x2
__device__ __forceinline__ void mfma_64x128(const char* As, const char* Bs,
                                            f32x4 acc[2][4], int lane,
                                            int wr, int wc)
{
  int g = lane >> 4;
  #pragma unroll
  for (int ks = 0; ks < 2; ++ks) {
    int kb = ks * 64 + (g << 4);
    bf16x8 af[2], bfr[4];
    #pragma unroll
    for (int m = 0; m < 2; ++m) af[m]  = fragS(As, wr * 32 + m * 16 + (lane & 15), kb);
    #pragma unroll
    for (int n = 0; n < 4; ++n) bfr[n] = fragS(Bs, wc * 64 + n * 16 + (lane & 15), kb);
    #pragma unroll
    for (int m = 0; m < 2; ++m)
      #pragma unroll
      for (int n = 0; n < 4; ++n)
        acc[m][n] = __builtin_amdgcn_mfma_f32_16x16x32_bf16(af[m], bfr[n], acc[m][n], 0, 0, 0);
  }
}

// ---------- QKV projection (z=0:Q, 1:K, 2:V), fused fp32->bf16 on A --------
// BM=64, BN=128: grid (512,1,3) -> 6 wg/CU available.
// Q,K out: [B,H,T,D]  V out: [B,H,D,T]

__global__ __launch_bounds__(256, 4) void proj_gemm(
    const float* qf, const float* kf, const float* vf,
    const u16* wqb, const u16* wkb, const u16* wvb,
    const float* bq, const float* bk, const float* bv,
    u16* qh, u16* kh, u16* vt)
{
  __shared__ alignas(16) char As[8192];     // [64][64] bf16, swizzled
  __shared__ alignas(16) char Bs[16384];    // [128][64] bf16, swizzled
  int tid = threadIdx.x;
  int bi = blockIdx.x & 63, bj = blockIdx.x >> 6;
  int z = blockIdx.z;
  const float* A = (z == 0) ? qf : (z == 1) ? kf : vf;
  const u16* W = (z == 0) ? wqb : (z == 1) ? wkb : wvb;
  const float* bias = (z == 0) ? bq : (z == 1) ? bk : bv;
  u16* dst = (z == 0) ? qh : (z == 1) ? kh : vt;

  int lane = tid & 63;
  int wr = (tid >> 7) & 1, wc = (tid >> 6) & 1;

  float4 pa[2], pb[2];
  loadA64(A + bi * 65536, tid, pa, pb);     // kt=0 prefetch

  f32x4 acc[2][4] = {};
  for (int kt = 0; kt < 16; ++kt) {
    writeA64(As, tid, pa, pb);
    stageSw<4>(W + bj * 131072 + kt * 64, Bs, tid);
    if (kt < 15)
      loadA64(A + bi * 65536 + (kt + 1) * 64, tid, pa, pb);  // hide under MFMA
    __syncthreads();
    mfma_64x128(As, Bs, acc, lane, wr, wc);
    __syncthreads();
  }

  int rbase = bi * 64 + wr * 32 + ((lane >> 4) << 2);
  int cbase = bj * 128 + wc * 64;
  #pragma unroll
  for (int n = 0; n < 4; ++n) {
    int col = cbase + n * 16 + (lane & 15);
    float bsv = bias[col];
    int h = col >> 6, d = col & 63;
    #pragma unroll
    for (int m = 0; m < 2; ++m) {
      #pragma unroll
      for (int r = 0; r < 4; ++r) {
        int R = rbase + m * 16 + r;
        int b = R >> 10, t = R & 1023;
        u16 val = b1(acc[m][n][r] + bsv);
        if (z < 2) dst[(((b * 16 + h) * 1024 + t) << 6) + d] = val;
        else       dst[(((b * 16 + h) * 64 + d) << 10) + t] = val;
      }
    }
  }
}

// ---------- output projection: attn[4096x1024] @ Wo^T + bo -> FP32 d_out ----
// BM=64, BN=128: grid 512 -> 2 wg/CU.

__global__ __launch_bounds__(256, 4) void out_gemm(
    const u16* attn, const u16* wob, const float* bo, float* out)
{
  __shared__ alignas(16) char As[8192];
  __shared__ alignas(16) char Bs[16384];
  int tid = threadIdx.x;
  int bi = blockIdx.x & 63, bj = blockIdx.x >> 6;

  int lane = tid & 63;
  int wr = (tid >> 7) & 1, wc = (tid >> 6) & 1;
  f32x4 acc[2][4] = {};
  for (int kt = 0; kt < 16; ++kt) {
    stageSw<2>(attn + bi * 65536  + kt * 64, As, tid);
    stageSw<4>(wob  + bj * 131072 + kt * 64, Bs, tid);
    __syncthreads();
    mfma_64x128(As, Bs, acc, lane, wr, wc);
    __syncthreads();
  }

  int rbase = bi * 64 + wr * 32 + ((lane >> 4) << 2);
  int cbase = bj * 128 + wc * 64;
  #pragma unroll
  for (int n = 0; n < 4; ++n) {
    int col = cbase + n * 16 + (lane & 15);
    float bsv = bo[col];
    #pragma unroll
    for (int m = 0; m < 2; ++m) {
      #pragma unroll
      for (int r = 0; r < 4; ++r) {
        int R = rbase + m * 16 + r;
        out[R * 1024 + col] = acc[m][n][r] + bsv;   // fp32 output
      }
    }
  }
}

// ---------- flash attention (unchanged from round 5) ----------

__global__ __launch_bounds__(256, 2) void attn_fwd(
    const u16* qh, const u16* kh, const u16* vt, u16* attnb)
{
  __shared__ alignas(16) u16 Ks[64 * 72];
  __shared__ alignas(16) u16 Vs[64 * 72];
  __shared__ alignas(16) u16 Pl[4][16 * 72];

  const float SC = 0.125f;           // 1/sqrt(64)
  const float RTHR = 64.0f;          // 8 nats / SC

  int tid = threadIdx.x, lane = tid & 63, w = tid >> 6;
  int g = lane >> 4;
  int q0 = blockIdx.x << 6;
  int bh = blockIdx.y;
  const u16* qbase = qh + bh * 65536;   // [t][d]
  const u16* kbase = kh + bh * 65536;   // [t][d]
  const u16* vbase = vt + bh * 65536;   // [d][t]

  bf16x8 qf[2];
  {
    int qrow = q0 + w * 16 + (lane & 15);
    const u16* p = qbase + qrow * 64 + (g << 3);
    qf[0] = *(const bf16x8*)p;
    qf[1] = *(const bf16x8*)(p + 32);
  }

  f32x4 ot[4] = {};
  float m_r = -3.0e38f, l_r = 0.f;   // m_r in RAW score units

  int sr = tid >> 2;                 // staging row 0..63
  int sj = (tid & 3) << 4;           // staging col {0,16,32,48}
  u16* pw = Pl[w];
  int prow = (lane & 15) * 72;

  for (int kv0 = 0; kv0 < 1024; kv0 += 64) {
    {
      const u16* ksrc = kbase + (kv0 + sr) * 64 + sj;
      const u16* vsrc = vbase + sr * 1024 + kv0 + sj;
      *(bf16x8*)(Ks + sr * 72 + sj)     = *(const bf16x8*)ksrc;
      *(bf16x8*)(Ks + sr * 72 + sj + 8) = *(const bf16x8*)(ksrc + 8);
      *(bf16x8*)(Vs + sr * 72 + sj)     = *(const bf16x8*)vsrc;
      *(bf16x8*)(Vs + sr * 72 + sj + 8) = *(const bf16x8*)(vsrc + 8);
    }
    __syncthreads();

    // S^T = K * Q^T (raw scores)
    f32x4 sc[4] = {};
    #pragma unroll
    for (int ks = 0; ks < 2; ++ks) {
      #pragma unroll
      for (int m = 0; m < 4; ++m) {
        bf16x8 kf = *(const bf16x8*)(Ks + (m * 16 + (lane & 15)) * 72 + ks * 32 + g * 8);
        sc[m] = __builtin_amdgcn_mfma_f32_16x16x32_bf16(kf, qf[ks], sc[m], 0, 0, 0);
      }
    }

    float vmax = -3.0e38f;
    #pragma unroll
    for (int m = 0; m < 4; ++m)
      #pragma unroll
      for (int r = 0; r < 4; ++r)
        vmax = fmaxf(vmax, sc[m][r]);
    vmax = fmaxf(vmax, __shfl_xor(vmax, 16, 64));
    vmax = fmaxf(vmax, __shfl_xor(vmax, 32, 64));

    if (!__all(vmax - m_r <= RTHR)) {    // T13 defer-max
      float mnew = fmaxf(m_r, vmax);
      float fac = __expf((m_r - mnew) * SC);
      l_r *= fac;
      #pragma unroll
      for (int dm = 0; dm < 4; ++dm) ot[dm] *= fac;
      m_r = mnew;
    }
    float nm = -m_r * SC;

    float psum = 0.f;
    u32 pp[4][2];
    #pragma unroll
    for (int m = 0; m < 4; ++m) {
      float p0 = __expf(fmaf(sc[m][0], SC, nm));
      float p1 = __expf(fmaf(sc[m][1], SC, nm));
      float p2 = __expf(fmaf(sc[m][2], SC, nm));
      float p3 = __expf(fmaf(sc[m][3], SC, nm));
      psum += (p0 + p1) + (p2 + p3);
      pp[m][0] = pk2(p0, p1);
      pp[m][1] = pk2(p2, p3);
    }
    psum += __shfl_xor(psum, 16, 64);
    psum += __shfl_xor(psum, 32, 64);
    l_r += psum;

    #pragma unroll
    for (int m = 0; m < 4; ++m) {
      u32* d = (u32*)(pw + prow + m * 16 + (g << 2));
      d[0] = pp[m][0];
      d[1] = pp[m][1];
    }

    // O^T += V^T * P^T
    #pragma unroll
    for (int ks = 0; ks < 2; ++ks) {
      bf16x8 pf = *(const bf16x8*)(pw + prow + ks * 32 + g * 8);
      #pragma unroll
      for (int dm = 0; dm < 4; ++dm) {
        bf16x8 vf = *(const bf16x8*)(Vs + (dm * 16 + (lane & 15)) * 72 + ks * 32 + g * 8);
        ot[dm] = __builtin_amdgcn_mfma_f32_16x16x32_bf16(vf, pf, ot[dm], 0, 0, 0);
      }
    }
    __syncthreads();
  }

  float inv = 1.0f / l_r;
  int b = bh >> 4, h = bh & 15;
  int tok = (b << 10) + q0 + w * 16 + (lane & 15);
  u16* obase = attnb + tok * 1024 + h * 64;
  #pragma unroll
  for (int dm = 0; dm < 4; ++dm) {
    int d0 = dm * 16 + (g << 2);
    u32* d = (u32*)(obase + d0);
    d[0] = pk2(ot[dm][0] * inv, ot[dm][1] * inv);
    d[1] = pk2(ot[dm][2] * inv, ot[dm][3] * inv);
  }
}

// ---------- launch ----------

extern "C" void kernel_launch(void* const* d_in, const int* in_sizes, int n_in,
                              void* d_out, int out_size, void* d_ws, size_t ws_size,
                              hipStream_t stream)
{
  const float* q  = (const float*)d_in[0];
  const float* k  = (const float*)d_in[1];
  const float* v  = (const float*)d_in[2];
  const float* Wq = (const float*)d_in[3];
  const float* bq = (const float*)d_in[4];
  const float* Wk = (const float*)d_in[5];
  const float* bk = (const float*)d_in[6];
  const float* Wv = (const float*)d_in[7];
  const float* bv = (const float*)d_in[8];
  const float* Wo = (const float*)d_in[9];
  const float* bo = (const float*)d_in[10];
  float* out = (float*)d_out;          // reference output dtype = float32

  u16* ws  = (u16*)d_ws;
  u16* wqb = ws;                    // 1M elems each (bf16)
  u16* wkb = wqb + (1u << 20);
  u16* wvb = wkb + (1u << 20);
  u16* wob = wvb + (1u << 20);
  u16* qhb = wob + (1u << 20);      // 4M each
  u16* khb = qhb + (4u << 20);
  u16* vtb = khb + (4u << 20);
  u16* atb = vtb + (4u << 20);      // total 40 MiB

  cvt_w<<<dim3(256, 4, 1), 256, 0, stream>>>(Wq, Wk, Wv, Wo, wqb, wkb, wvb, wob);
  proj_gemm<<<dim3(512, 1, 3), 256, 0, stream>>>(q, k, v, wqb, wkb, wvb,
                                                 bq, bk, bv, qhb, khb, vtb);
  attn_fwd<<<dim3(16, 64, 1), 256, 0, stream>>>(qhb, khb, vtb, atb);
  out_gemm<<<dim3(512, 1, 1), 256, 0, stream>>>(atb, wob, bo, out);
}

// Round 9
// 220.538 us; speedup vs baseline: 1.0813x; 1.0136x over previous
//
#include <hip/hip_runtime.h>
#include <stdint.h>

typedef unsigned short u16;
typedef unsigned int   u32;
typedef __bf16 bf16;
typedef bf16  bf16x2 __attribute__((ext_vector_type(2)));
typedef bf16  bf16x8 __attribute__((ext_vector_type(8)));
typedef float f32x4  __attribute__((ext_vector_type(4)));

#define AS1 __attribute__((address_space(1)))
#define AS3 __attribute__((address_space(3)))

// ---------- helpers ----------

__device__ __forceinline__ u32 pk2(float lo, float hi) {
  bf16x2 t;
  t[0] = (bf16)lo;
  t[1] = (bf16)hi;
  return __builtin_bit_cast(u32, t);
}

__device__ __forceinline__ u16 b1(float f) {
  bf16 t = (bf16)f;
  return __builtin_bit_cast(u16, t);
}

__device__ __forceinline__ void gload_lds16(const void* src, void* dst) {
  __builtin_amdgcn_global_load_lds((const AS1 void*)src, (AS3 void*)dst, 16, 0, 0);
}

// swizzled fragment read from a [rows][128B] LDS tile: byte ^= (row&7)<<4
__device__ __forceinline__ bf16x8 fragS(const char* lds, int row, int kbyte) {
  return *(const bf16x8*)(lds + row * 128 + (kbyte ^ ((row & 7) << 4)));
}

// ---------- fp32 -> bf16 conversion (weights only) ----------

__global__ __launch_bounds__(256) void cvt_w(
    const float* wq, const float* wk, const float* wv, const float* wo,
    u16* wqb, u16* wkb, u16* wvb, u16* wob)
{
  const float* src; u16* dst;
  switch (blockIdx.y) {
    case 0: src = wq; dst = wqb; break;
    case 1: src = wk; dst = wkb; break;
    case 2: src = wv; dst = wvb; break;
    default: src = wo; dst = wob; break;
  }
  const int n4 = 262144;
  int stride = gridDim.x * blockDim.x;
  for (int i = blockIdx.x * blockDim.x + threadIdx.x; i < n4; i += stride) {
    float4 f = ((const float4*)src)[i];
    uint2 o;
    o.x = pk2(f.x, f.y);
    o.y = pk2(f.z, f.w);
    ((uint2*)dst)[i] = o;
  }
}

// ---------- GEMM staging ----------

// bf16 source -> LDS [8*NC*4 rows][64k] via global_load_lds, pre-swizzled src
template<int NC>
__device__ __forceinline__ void stageSw(const u16* gtile, char* lds, int tid)
{
  int w = tid >> 6, lane = tid & 63;
  int rr = lane >> 3;
  int cb = (lane & 7) << 4;
  #pragma unroll
  for (int i = 0; i < NC; ++i) {
    int c = i * 4 + w;
    int r = c * 8 + rr;
    gload_lds16((const char*)(gtile + r * 1024) + (cb ^ (rr << 4)), lds + c * 1024);
  }
}

// fp32 A prefetch: 64 rows, per-thread 2x32B
__device__ __forceinline__ void loadA64(const float* gA, int tid,
                                        float4* pa, float4* pb)
{
  int r0 = tid >> 3, c8 = (tid & 7) << 3;
  #pragma unroll
  for (int i = 0; i < 2; ++i) {
    const float* p = gA + (i * 32 + r0) * 1024 + c8;
    pa[i] = *(const float4*)p;
    pb[i] = *(const float4*)(p + 4);
  }
}

// cvt + swizzled ds_write into [64][64] bf16 LDS
__device__ __forceinline__ void writeA64(char* lds, int tid,
                                         const float4* pa, const float4* pb)
{
  int r0 = tid >> 3, cb = (tid & 7) << 4;
  #pragma unroll
  for (int i = 0; i < 2; ++i) {
    int r = i * 32 + r0;
    uint4 o;
    o.x = pk2(pa[i].x, pa[i].y);
    o.y = pk2(pa[i].z, pa[i].w);
    o.z = pk2(pb[i].x, pb[i].y);
    o.w = pk2(pb[i].z, pb[i].w);
    *(uint4*)(lds + r * 128 + (cb ^ ((r & 7) << 4))) = o;
  }
}

// one K-tile of MFMAs: BM=64 (2 m-frags) x BN=128 (4 n-frags), waves 2x2
__device__ __forceinline__ void mfma_64x128(const char* As, const char* Bs,
                                            f32x4 acc[2][4], int lane,
                                            int wr, int wc)
{
  int g = lane >> 4;
  #pragma unroll
  for (int ks = 0; ks < 2; ++ks) {
    int kb = ks * 64 + (g << 4);
    bf16x8 af[2], bfr[4];
    #pragma unroll
    for (int m = 0; m < 2; ++m) af[m]  = fragS(As, wr * 32 + m * 16 + (lane & 15), kb);
    #pragma unroll
    for (int n = 0; n < 4; ++n) bfr[n] = fragS(Bs, wc * 64 + n * 16 + (lane & 15), kb);
    #pragma unroll
    for (int m = 0; m < 2; ++m)
      #pragma unroll
      for (int n = 0; n < 4; ++n)
        acc[m][n] = __builtin_amdgcn_mfma_f32_16x16x32_bf16(af[m], bfr[n], acc[m][n], 0, 0, 0);
  }
}

// ---------- QKV projection (z=0:Q, 1:K, 2:V) ----------
// BM=64, BN=128, 2-phase LDS double-buffer: stage t+1 while MFMA(t),
// ONE barrier per K-step. LDS 48 KB -> 3 wg/CU.

__global__ __launch_bounds__(256, 3) void proj_gemm(
    const float* qf, const float* kf, const float* vf,
    const u16* wqb, const u16* wkb, const u16* wvb,
    const float* bq, const float* bk, const float* bv,
    u16* qh, u16* kh, u16* vt)
{
  __shared__ alignas(16) char As[2][8192];
  __shared__ alignas(16) char Bs[2][16384];
  int tid = threadIdx.x;
  int bi = blockIdx.x & 63, bj = blockIdx.x >> 6;
  int z = blockIdx.z;
  const float* A = (z == 0) ? qf : (z == 1) ? kf : vf;
  const u16* W = (z == 0) ? wqb : (z == 1) ? wkb : wvb;
  const float* bias = (z == 0) ? bq : (z == 1) ? bk : bv;
  u16* dst = (z == 0) ? qh : (z == 1) ? kh : vt;

  int lane = tid & 63;
  int wr = (tid >> 7) & 1, wc = (tid >> 6) & 1;

  float4 pa[2], pb[2];
  // prologue: tile 0 into buf 0
  loadA64(A + bi * 65536, tid, pa, pb);
  stageSw<4>(W + bj * 131072, Bs[0], tid);
  writeA64(As[0], tid, pa, pb);
  loadA64(A + bi * 65536 + 64, tid, pa, pb);     // t=1 regs
  __syncthreads();

  f32x4 acc[2][4] = {};
  int cur = 0;
  for (int kt = 0; kt < 16; ++kt) {
    if (kt < 15) {
      stageSw<4>(W + bj * 131072 + (kt + 1) * 64, Bs[cur ^ 1], tid);
      writeA64(As[cur ^ 1], tid, pa, pb);
      if (kt < 14)
        loadA64(A + bi * 65536 + (kt + 2) * 64, tid, pa, pb);
    }
    mfma_64x128(As[cur], Bs[cur], acc, lane, wr, wc);
    __syncthreads();
    cur ^= 1;
  }

  int rbase = bi * 64 + wr * 32 + ((lane >> 4) << 2);
  int cbase = bj * 128 + wc * 64;
  #pragma unroll
  for (int n = 0; n < 4; ++n) {
    int col = cbase + n * 16 + (lane & 15);
    float bsv = bias[col];
    int h = col >> 6, d = col & 63;
    #pragma unroll
    for (int m = 0; m < 2; ++m) {
      #pragma unroll
      for (int r = 0; r < 4; ++r) {
        int R = rbase + m * 16 + r;
        int b = R >> 10, t = R & 1023;
        u16 val = b1(acc[m][n][r] + bsv);
        if (z < 2) dst[(((b * 16 + h) * 1024 + t) << 6) + d] = val;
        else       dst[(((b * 16 + h) * 64 + d) << 10) + t] = val;
      }
    }
  }
}

// ---------- output projection: 2-phase dbuf, fp32 out ----------

__global__ __launch_bounds__(256, 3) void out_gemm(
    const u16* attn, const u16* wob, const float* bo, float* out)
{
  __shared__ alignas(16) char As[2][8192];
  __shared__ alignas(16) char Bs[2][16384];
  int tid = threadIdx.x;
  int bi = blockIdx.x & 63, bj = blockIdx.x >> 6;

  int lane = tid & 63;
  int wr = (tid >> 7) & 1, wc = (tid >> 6) & 1;

  // prologue
  stageSw<2>(attn + bi * 65536, As[0], tid);
  stageSw<4>(wob + bj * 131072, Bs[0], tid);
  __syncthreads();

  f32x4 acc[2][4] = {};
  int cur = 0;
  for (int kt = 0; kt < 16; ++kt) {
    if (kt < 15) {
      stageSw<2>(attn + bi * 65536  + (kt + 1) * 64, As[cur ^ 1], tid);
      stageSw<4>(wob  + bj * 131072 + (kt + 1) * 64, Bs[cur ^ 1], tid);
    }
    mfma_64x128(As[cur], Bs[cur], acc, lane, wr, wc);
    __syncthreads();
    cur ^= 1;
  }

  int rbase = bi * 64 + wr * 32 + ((lane >> 4) << 2);
  int cbase = bj * 128 + wc * 64;
  #pragma unroll
  for (int n = 0; n < 4; ++n) {
    int col = cbase + n * 16 + (lane & 15);
    float bsv = bo[col];
    #pragma unroll
    for (int m = 0; m < 2; ++m) {
      #pragma unroll
      for (int r = 0; r < 4; ++r) {
        int R = rbase + m * 16 + r;
        out[R * 1024 + col] = acc[m][n][r] + bsv;
      }
    }
  }
}

// ---------- flash attention: + T14 issue-early K/V prefetch ----------

__global__ __launch_bounds__(256, 2) void attn_fwd(
    const u16* qh, const u16* kh, const u16* vt, u16* attnb)
{
  __shared__ alignas(16) u16 Ks[64 * 72];
  __shared__ alignas(16) u16 Vs[64 * 72];
  __shared__ alignas(16) u16 Pl[4][16 * 72];

  const float SC = 0.125f;
  const float RTHR = 64.0f;

  int tid = threadIdx.x, lane = tid & 63, w = tid >> 6;
  int g = lane >> 4;
  int q0 = blockIdx.x << 6;
  int bh = blockIdx.y;
  const u16* qbase = qh + bh * 65536;   // [t][d]
  const u16* kbase = kh + bh * 65536;   // [t][d]
  const u16* vbase = vt + bh * 65536;   // [d][t]

  bf16x8 qf[2];
  {
    int qrow = q0 + w * 16 + (lane & 15);
    const u16* p = qbase + qrow * 64 + (g << 3);
    qf[0] = *(const bf16x8*)p;
    qf[1] = *(const bf16x8*)(p + 32);
  }

  f32x4 ot[4] = {};
  float m_r = -3.0e38f, l_r = 0.f;

  int sr = tid >> 2;
  int sj = (tid & 3) << 4;
  u16* pw = Pl[w];
  int prow = (lane & 15) * 72;

  const u16* ksrc0 = kbase + sr * 64 + sj;
  const u16* vsrc0 = vbase + sr * 1024 + sj;

  // prefetch tile 0 into regs
  bf16x8 kr0, kr1, vr0, vr1;
  kr0 = *(const bf16x8*)(ksrc0);
  kr1 = *(const bf16x8*)(ksrc0 + 8);
  vr0 = *(const bf16x8*)(vsrc0);
  vr1 = *(const bf16x8*)(vsrc0 + 8);

  for (int kv0 = 0; kv0 < 1024; kv0 += 64) {
    // write staged regs to LDS
    *(bf16x8*)(Ks + sr * 72 + sj)     = kr0;
    *(bf16x8*)(Ks + sr * 72 + sj + 8) = kr1;
    *(bf16x8*)(Vs + sr * 72 + sj)     = vr0;
    *(bf16x8*)(Vs + sr * 72 + sj + 8) = vr1;
    __syncthreads();

    // T14: issue next tile's loads early; latency hides under compute
    if (kv0 < 960) {
      const u16* kn = ksrc0 + (kv0 + 64) * 64;
      const u16* vn = vsrc0 + (kv0 + 64);
      kr0 = *(const bf16x8*)(kn);
      kr1 = *(const bf16x8*)(kn + 8);
      vr0 = *(const bf16x8*)(vn);
      vr1 = *(const bf16x8*)(vn + 8);
    }

    // S^T = K * Q^T (raw scores)
    f32x4 sc[4] = {};
    #pragma unroll
    for (int ks = 0; ks < 2; ++ks) {
      #pragma unroll
      for (int m = 0; m < 4; ++m) {
        bf16x8 kf = *(const bf16x8*)(Ks + (m * 16 + (lane & 15)) * 72 + ks * 32 + g * 8);
        sc[m] = __builtin_amdgcn_mfma_f32_16x16x32_bf16(kf, qf[ks], sc[m], 0, 0, 0);
      }
    }

    float vmax = -3.0e38f;
    #pragma unroll
    for (int m = 0; m < 4; ++m)
      #pragma unroll
      for (int r = 0; r < 4; ++r)
        vmax = fmaxf(vmax, sc[m][r]);
    vmax = fmaxf(vmax, __shfl_xor(vmax, 16, 64));
    vmax = fmaxf(vmax, __shfl_xor(vmax, 32, 64));

    if (!__all(vmax - m_r <= RTHR)) {    // T13 defer-max
      float mnew = fmaxf(m_r, vmax);
      float fac = __expf((m_r - mnew) * SC);
      l_r *= fac;
      #pragma unroll
      for (int dm = 0; dm < 4; ++dm) ot[dm] *= fac;
      m_r = mnew;
    }
    float nm = -m_r * SC;

    float psum = 0.f;
    u32 pp[4][2];
    #pragma unroll
    for (int m = 0; m < 4; ++m) {
      float p0 = __expf(fmaf(sc[m][0], SC, nm));
      float p1 = __expf(fmaf(sc[m][1], SC, nm));
      float p2 = __expf(fmaf(sc[m][2], SC, nm));
      float p3 = __expf(fmaf(sc[m][3], SC, nm));
      psum += (p0 + p1) + (p2 + p3);
      pp[m][0] = pk2(p0, p1);
      pp[m][1] = pk2(p2, p3);
    }
    psum += __shfl_xor(psum, 16, 64);
    psum += __shfl_xor(psum, 32, 64);
    l_r += psum;

    #pragma unroll
    for (int m = 0; m < 4; ++m) {
      u32* d = (u32*)(pw + prow + m * 16 + (g << 2));
      d[0] = pp[m][0];
      d[1] = pp[m][1];
    }

    // O^T += V^T * P^T
    #pragma unroll
    for (int ks = 0; ks < 2; ++ks) {
      bf16x8 pf = *(const bf16x8*)(pw + prow + ks * 32 + g * 8);
      #pragma unroll
      for (int dm = 0; dm < 4; ++dm) {
        bf16x8 vf = *(const bf16x8*)(Vs + (dm * 16 + (lane & 15)) * 72 + ks * 32 + g * 8);
        ot[dm] = __builtin_amdgcn_mfma_f32_16x16x32_bf16(vf, pf, ot[dm], 0, 0, 0);
      }
    }
    __syncthreads();
  }

  float inv = 1.0f / l_r;
  int b = bh >> 4, h = bh & 15;
  int tok = (b << 10) + q0 + w * 16 + (lane & 15);
  u16* obase = attnb + tok * 1024 + h * 64;
  #pragma unroll
  for (int dm = 0; dm < 4; ++dm) {
    int d0 = dm * 16 + (g << 2);
    u32* d = (u32*)(obase + d0);
    d[0] = pk2(ot[dm][0] * inv, ot[dm][1] * inv);
    d[1] = pk2(ot[dm][2] * inv, ot[dm][3] * inv);
  }
}

// ---------- launch ----------

extern "C" void kernel_launch(void* const* d_in, const int* in_sizes, int n_in,
                              void* d_out, int out_size, void* d_ws, size_t ws_size,
                              hipStream_t stream)
{
  const float* q  = (const float*)d_in[0];
  const float* k  = (const float*)d_in[1];
  const float* v  = (const float*)d_in[2];
  const float* Wq = (const float*)d_in[3];
  const float* bq = (const float*)d_in[4];
  const float* Wk = (const float*)d_in[5];
  const float* bk = (const float*)d_in[6];
  const float* Wv = (const float*)d_in[7];
  const float* bv = (const float*)d_in[8];
  const float* Wo = (const float*)d_in[9];
  const float* bo = (const float*)d_in[10];
  float* out = (float*)d_out;

  u16* ws  = (u16*)d_ws;
  u16* wqb = ws;
  u16* wkb = wqb + (1u << 20);
  u16* wvb = wkb + (1u << 20);
  u16* wob = wvb + (1u << 20);
  u16* qhb = wob + (1u << 20);
  u16* khb = qhb + (4u << 20);
  u16* vtb = khb + (4u << 20);
  u16* atb = vtb + (4u << 20);

  cvt_w<<<dim3(256, 4, 1), 256, 0, stream>>>(Wq, Wk, Wv, Wo, wqb, wkb, wvb, wob);
  proj_gemm<<<dim3(512, 1, 3), 256, 0, stream>>>(q, k, v, wqb, wkb, wvb,
                                                 bq, bk, bv, qhb, khb, vtb);
  attn_fwd<<<dim3(16, 64, 1), 256, 0, stream>>>(qhb, khb, vtb, atb);
  out_gemm<<<dim3(512, 1, 1), 256, 0, stream>>>(atb, wob, bo, out);
}